// Round 1
// baseline (498.722 us; speedup 1.0000x reference)
//
#include <hip/hip_runtime.h>

typedef unsigned short u16;
typedef u16 u16x8 __attribute__((ext_vector_type(8)));
typedef u16 u16x4v __attribute__((ext_vector_type(4)));
typedef __bf16 bf16x8 __attribute__((ext_vector_type(8)));
typedef float f32x4 __attribute__((ext_vector_type(4)));

__device__ __forceinline__ u16 f2bf(float f) {
  unsigned u = __builtin_bit_cast(unsigned, f);
  u += 0x7FFF + ((u >> 16) & 1);   // RNE
  return (u16)(u >> 16);
}

__device__ __forceinline__ f32x4 mfma16(u16x8 a, u16x8 b, f32x4 c) {
  return __builtin_amdgcn_mfma_f32_16x16x32_bf16(
      __builtin_bit_cast(bf16x8, a), __builtin_bit_cast(bf16x8, b), c, 0, 0, 0);
}

// ---------------------------------------------------------------- constants
constexpr int DM   = 1024;   // d_model
constexpr int GK   = 1024;   // GEMM K
constexpr int SEQ  = 2048;
constexpr int NB   = 4;
constexpr int NH   = 16;
constexpr int BK   = 64;     // GEMM K-tile
constexpr int LSTR = 72;     // padded LDS stride (bf16 elems)

// ---------------------------------------------------------------- weight transpose+cast
__global__ void transpose_cast_kernel(const float* __restrict__ W, u16* __restrict__ Wt) {
  __shared__ float tile[32][33];
  const int tx = threadIdx.x;          // 0..31
  const int ty = threadIdx.y;          // 0..7
  const int n0 = blockIdx.x * 32;
  const int k0 = blockIdx.y * 32;
#pragma unroll
  for (int i = 0; i < 4; ++i)
    tile[ty + i * 8][tx] = W[(size_t)(k0 + ty + i * 8) * DM + n0 + tx];
  __syncthreads();
#pragma unroll
  for (int i = 0; i < 4; ++i)
    Wt[(size_t)(n0 + ty + i * 8) * DM + k0 + tx] = f2bf(tile[tx][ty + i * 8]);
}

// ---------------------------------------------------------------- valid_len from key padding mask
__global__ void vlen_kernel(const int* __restrict__ mask, int* __restrict__ vlen) {
  const int b = blockIdx.x;
  const int t = threadIdx.x;
  __shared__ int cnt[256];
  int c = 0;
  for (int s = t; s < SEQ; s += 256) c += (mask[b * SEQ + s] == 0) ? 1 : 0;
  cnt[t] = c;
  __syncthreads();
  for (int off = 128; off > 0; off >>= 1) {
    if (t < off) cnt[t] += cnt[t + off];
    __syncthreads();
  }
  if (t == 0) vlen[b] = cnt[0];
}

// ---------------------------------------------------------------- 128x128 MFMA GEMM
// C[M=8192,N=1024] = A[M,K=1024] @ Bt[N,K]^T + bias
// out_mode 0: bf16 [B,H,S,64]   (Q,K)
// out_mode 1: bf16 [B,H,64,S]   (V transposed)
// out_mode 2: f32 row-major     (final)
template <bool A_FP32>
__global__ __launch_bounds__(256) void gemm_kernel(const void* __restrict__ Av,
                                                   const u16* __restrict__ Bt,
                                                   const float* __restrict__ bias,
                                                   void* __restrict__ outv,
                                                   int out_mode) {
  __shared__ __align__(16) u16 lds_a[128 * LSTR];
  __shared__ __align__(16) u16 lds_b[128 * LSTR];
  const int tid  = threadIdx.x;
  const int lane = tid & 63;
  const int w    = tid >> 6;
  const int wm   = (w >> 1) * 64;
  const int wn   = (w & 1) * 64;
  const int lrow = lane & 15;
  const int lk   = (lane >> 4) * 8;
  const int n0   = blockIdx.x * 128;
  const int m0   = blockIdx.y * 128;

  f32x4 acc[4][4] = {};

  for (int kt = 0; kt < GK; kt += BK) {
    __syncthreads();
    if (A_FP32) {
      const float* A = (const float*)Av;
#pragma unroll
      for (int i = 0; i < 8; ++i) {
        int idx = tid + i * 256;
        int row = idx >> 4, q = idx & 15;
        float4 v = *(const float4*)(A + (size_t)(m0 + row) * GK + kt + q * 4);
        u16x4v hv = {f2bf(v.x), f2bf(v.y), f2bf(v.z), f2bf(v.w)};
        *(u16x4v*)(&lds_a[row * LSTR + q * 4]) = hv;
      }
    } else {
      const u16* A = (const u16*)Av;
#pragma unroll
      for (int i = 0; i < 4; ++i) {
        int idx = tid + i * 256;
        int row = idx >> 3, q = idx & 7;
        *(u16x8*)(&lds_a[row * LSTR + q * 8]) =
            *(const u16x8*)(A + (size_t)(m0 + row) * GK + kt + q * 8);
      }
    }
#pragma unroll
    for (int i = 0; i < 4; ++i) {
      int idx = tid + i * 256;
      int row = idx >> 3, q = idx & 7;
      *(u16x8*)(&lds_b[row * LSTR + q * 8]) =
          *(const u16x8*)(Bt + (size_t)(n0 + row) * GK + kt + q * 8);
    }
    __syncthreads();
#pragma unroll
    for (int kk = 0; kk < BK; kk += 32) {
      u16x8 am[4], bn[4];
#pragma unroll
      for (int m = 0; m < 4; ++m)
        am[m] = *(const u16x8*)(&lds_a[(wm + m * 16 + lrow) * LSTR + kk + lk]);
#pragma unroll
      for (int n = 0; n < 4; ++n)
        bn[n] = *(const u16x8*)(&lds_b[(wn + n * 16 + lrow) * LSTR + kk + lk]);
#pragma unroll
      for (int m = 0; m < 4; ++m)
#pragma unroll
        for (int n = 0; n < 4; ++n)
          acc[m][n] = mfma16(am[m], bn[n], acc[m][n]);
    }
  }

  const int r0 = (lane >> 4) * 4;
#pragma unroll
  for (int m = 0; m < 4; ++m) {
#pragma unroll
    for (int n = 0; n < 4; ++n) {
      const int col = n0 + wn + n * 16 + lrow;
      const float bval = bias[col];
#pragma unroll
      for (int r = 0; r < 4; ++r) {
        const int row = m0 + wm + m * 16 + r0 + r;
        const float v = acc[m][n][r] + bval;
        if (out_mode == 2) {
          ((float*)outv)[(size_t)row * DM + col] = v;
        } else {
          const int bb = row >> 11, s = row & (SEQ - 1);
          const int h = col >> 6, d = col & 63;
          size_t off;
          if (out_mode == 0) off = (((size_t)(bb * NH + h)) * SEQ + s) * 64 + d;
          else               off = (((size_t)(bb * NH + h)) * 64 + d) * SEQ + s;
          ((u16*)outv)[off] = f2bf(v);
        }
      }
    }
  }
}

// ---------------------------------------------------------------- flash attention
// Q,K: bf16 [B,H,S,64]; Vt: bf16 [B,H,64,S]; att out: bf16 [B,S,H*64]
__global__ __launch_bounds__(256) void attn_kernel(const u16* __restrict__ Qm,
                                                   const u16* __restrict__ Km,
                                                   const u16* __restrict__ Vtm,
                                                   const int* __restrict__ vlen,
                                                   u16* __restrict__ att) {
  __shared__ __align__(16) u16 lds_k[64 * 72];
  __shared__ __align__(16) u16 lds_v[64 * 72];
  __shared__ __align__(16) u16 lds_p[4][16 * 72];
  const int tid  = threadIdx.x;
  const int lane = tid & 63;
  const int w    = tid >> 6;
  const int lrow = lane & 15;
  const int lk   = (lane >> 4) * 8;
  const int r0   = (lane >> 4) * 4;
  const int qb   = blockIdx.x;
  const int bh   = blockIdx.y;
  const int b    = bh >> 4;
  const int h    = bh & 15;
  const int valid = vlen[b];
  const int q0   = qb * 64;
  const int q0w  = q0 + w * 16;
  const float NEG_INF = -__builtin_inff();

  const u16* Qb = Qm + ((size_t)bh * SEQ + q0w) * 64;
  u16x8 aq[2];
  aq[0] = *(const u16x8*)(Qb + lrow * 64 + lk);
  aq[1] = *(const u16x8*)(Qb + lrow * 64 + lk + 32);

  float m_run[4], l_run[4];
  f32x4 acc[4] = {};
#pragma unroll
  for (int r = 0; r < 4; ++r) { m_run[r] = NEG_INF; l_run[r] = 0.f; }

  const int cb = (q0 + 63) >> 6;
  const int vb = (valid - 1) >> 6;
  const int kb_max = cb < vb ? cb : vb;

  for (int kb = 0; kb <= kb_max; ++kb) {
    __syncthreads();
    const u16* Kb = Km + ((size_t)bh * SEQ + kb * 64) * 64;
    const u16* Vb = Vtm + (size_t)bh * 64 * SEQ + kb * 64;
#pragma unroll
    for (int i = 0; i < 2; ++i) {
      int idx = tid + i * 256;
      int row = idx >> 3, qq = idx & 7;
      *(u16x8*)(&lds_k[row * 72 + qq * 8]) = *(const u16x8*)(Kb + row * 64 + qq * 8);
      *(u16x8*)(&lds_v[row * 72 + qq * 8]) = *(const u16x8*)(Vb + (size_t)row * SEQ + qq * 8);
    }
    __syncthreads();

    // QK^T
    f32x4 sfr[4];
#pragma unroll
    for (int kblk = 0; kblk < 4; ++kblk) {
      sfr[kblk] = (f32x4){0.f, 0.f, 0.f, 0.f};
#pragma unroll
      for (int dh = 0; dh < 2; ++dh) {
        u16x8 bk = *(const u16x8*)(&lds_k[(kblk * 16 + lrow) * 72 + dh * 32 + lk]);
        sfr[kblk] = mfma16(aq[dh], bk, sfr[kblk]);
      }
    }

    // scale + mask + row max
    const int kbase = kb * 64;
    float mx[4] = {NEG_INF, NEG_INF, NEG_INF, NEG_INF};
#pragma unroll
    for (int kblk = 0; kblk < 4; ++kblk) {
      const int kg = kbase + kblk * 16 + lrow;
      const bool kv = (kg < valid);
#pragma unroll
      for (int r = 0; r < 4; ++r) {
        const int qg = q0w + r0 + r;
        float sv = sfr[kblk][r] * 0.125f;
        if (kg > qg || !kv) sv = NEG_INF;
        sfr[kblk][r] = sv;
        mx[r] = fmaxf(mx[r], sv);
      }
    }
#pragma unroll
    for (int r = 0; r < 4; ++r) {
#pragma unroll
      for (int msk = 1; msk < 16; msk <<= 1)
        mx[r] = fmaxf(mx[r], __shfl_xor(mx[r], msk));
    }
    float scale_r[4], rs[4];
#pragma unroll
    for (int r = 0; r < 4; ++r) {
      const float mnew = fmaxf(m_run[r], mx[r]);
      scale_r[r] = __expf(m_run[r] - mnew);
      m_run[r] = mnew;
      rs[r] = 0.f;
    }
    // P = exp(S - m), write bf16 to per-wave LDS
#pragma unroll
    for (int kblk = 0; kblk < 4; ++kblk) {
#pragma unroll
      for (int r = 0; r < 4; ++r) {
        const float p = __expf(sfr[kblk][r] - m_run[r]);
        rs[r] += p;
        lds_p[w][(r0 + r) * 72 + kblk * 16 + lrow] = f2bf(p);
      }
    }
#pragma unroll
    for (int r = 0; r < 4; ++r) {
#pragma unroll
      for (int msk = 1; msk < 16; msk <<= 1)
        rs[r] += __shfl_xor(rs[r], msk);
      l_run[r] = l_run[r] * scale_r[r] + rs[r];
    }
#pragma unroll
    for (int d = 0; d < 4; ++d)
#pragma unroll
      for (int r = 0; r < 4; ++r)
        acc[d][r] *= scale_r[r];

    asm volatile("s_waitcnt lgkmcnt(0)" ::: "memory");  // P writes visible to own wave

    // PV
#pragma unroll
    for (int d = 0; d < 4; ++d) {
#pragma unroll
      for (int kkk = 0; kkk < 2; ++kkk) {
        u16x8 ap = *(const u16x8*)(&lds_p[w][lrow * 72 + kkk * 32 + lk]);
        u16x8 av = *(const u16x8*)(&lds_v[(d * 16 + lrow) * 72 + kkk * 32 + lk]);
        acc[d] = mfma16(ap, av, acc[d]);
      }
    }
  }

  // epilogue: att[b][q][h*64+d]
#pragma unroll
  for (int d = 0; d < 4; ++d) {
#pragma unroll
    for (int r = 0; r < 4; ++r) {
      const int qg = q0w + r0 + r;
      const float v = acc[d][r] / l_run[r];
      att[((size_t)(b * SEQ + qg)) * DM + h * 64 + d * 16 + lrow] = f2bf(v);
    }
  }
}

// ---------------------------------------------------------------- launch
extern "C" void kernel_launch(void* const* d_in, const int* in_sizes, int n_in,
                              void* d_out, int out_size, void* d_ws, size_t ws_size,
                              hipStream_t stream) {
  const float* q_in = (const float*)d_in[0];
  const float* k_in = (const float*)d_in[1];
  const float* v_in = (const float*)d_in[2];
  const int*   kpm  = (const int*)d_in[3];
  const float* Wq   = (const float*)d_in[4];
  const float* bq   = (const float*)d_in[5];
  const float* Wk   = (const float*)d_in[6];
  const float* bk   = (const float*)d_in[7];
  const float* Wv   = (const float*)d_in[8];
  const float* bv   = (const float*)d_in[9];
  const float* Wo   = (const float*)d_in[10];
  const float* bo   = (const float*)d_in[11];

  char* ws = (char*)d_ws;
  const size_t WSZ = (size_t)1 << 21;   // 2 MB per transposed weight
  const size_t TSZ = (size_t)1 << 24;   // 16 MB per bf16 [8192,1024] tensor
  u16* wq_t = (u16*)(ws);
  u16* wk_t = (u16*)(ws + WSZ);
  u16* wv_t = (u16*)(ws + 2 * WSZ);
  u16* wo_t = (u16*)(ws + 3 * WSZ);
  u16* Qm   = (u16*)(ws + 4 * WSZ);
  u16* Km   = (u16*)(ws + 4 * WSZ + TSZ);
  u16* Vtm  = (u16*)(ws + 4 * WSZ + 2 * TSZ);
  u16* attb = (u16*)(ws + 4 * WSZ + 3 * TSZ);
  int* vlen = (int*)(ws + 4 * WSZ + 4 * TSZ);

  dim3 tb(32, 8), tg(32, 32);
  transpose_cast_kernel<<<tg, tb, 0, stream>>>(Wq, wq_t);
  transpose_cast_kernel<<<tg, tb, 0, stream>>>(Wk, wk_t);
  transpose_cast_kernel<<<tg, tb, 0, stream>>>(Wv, wv_t);
  transpose_cast_kernel<<<tg, tb, 0, stream>>>(Wo, wo_t);
  vlen_kernel<<<NB, 256, 0, stream>>>(kpm, vlen);

  dim3 gg(8, 64);
  gemm_kernel<true><<<gg, 256, 0, stream>>>(q_in, wq_t, bq, Qm, 0);
  gemm_kernel<true><<<gg, 256, 0, stream>>>(k_in, wk_t, bk, Km, 0);
  gemm_kernel<true><<<gg, 256, 0, stream>>>(v_in, wv_t, bv, Vtm, 1);

  attn_kernel<<<dim3(32, 64), 256, 0, stream>>>(Qm, Km, Vtm, vlen, attb);

  gemm_kernel<false><<<gg, 256, 0, stream>>>(attb, wo_t, bo, d_out, 2);
}

// Round 6
// 417.293 us; speedup vs baseline: 1.1951x; 1.1951x over previous
//
#include <hip/hip_runtime.h>

typedef unsigned short u16;
typedef unsigned int u32;
typedef u16 u16x8 __attribute__((ext_vector_type(8)));
typedef u16 u16x4v __attribute__((ext_vector_type(4)));
typedef u32 u32x2 __attribute__((ext_vector_type(2)));
typedef u32 u32x4 __attribute__((ext_vector_type(4)));
typedef __bf16 bf16x8 __attribute__((ext_vector_type(8)));
typedef float f32x4 __attribute__((ext_vector_type(4)));
typedef float f32x16 __attribute__((ext_vector_type(16)));

__device__ __forceinline__ u16 f2bf(float f) {
  unsigned u = __builtin_bit_cast(unsigned, f);
  u += 0x7FFF + ((u >> 16) & 1);   // RNE
  return (u16)(u >> 16);
}

__device__ __forceinline__ float fast_exp2(float x) {
  return __builtin_amdgcn_exp2f(x);
}

__device__ __forceinline__ f32x4 mfma16(u16x8 a, u16x8 b, f32x4 c) {
  return __builtin_amdgcn_mfma_f32_16x16x32_bf16(
      __builtin_bit_cast(bf16x8, a), __builtin_bit_cast(bf16x8, b), c, 0, 0, 0);
}

__device__ __forceinline__ f32x16 mfma32(u16x8 a, u16x8 b, f32x16 c) {
  return __builtin_amdgcn_mfma_f32_32x32x16_bf16(
      __builtin_bit_cast(bf16x8, a), __builtin_bit_cast(bf16x8, b), c, 0, 0, 0);
}

__device__ __forceinline__ u32 cvt_pk_bf16(float lo, float hi) {
  u32 r;
  asm("v_cvt_pk_bf16_f32 %0, %1, %2" : "=v"(r) : "v"(lo), "v"(hi));
  return r;
}

// ---------------------------------------------------------------- constants
constexpr int DM   = 1024;   // d_model
constexpr int GK   = 1024;   // GEMM K
constexpr int SEQ  = 2048;
constexpr int NB   = 4;
constexpr int NH   = 16;
constexpr int BK   = 64;     // GEMM K-tile
constexpr int LSTR = 72;     // padded LDS stride (bf16 elems)

// ---------------------------------------------------------------- weight transpose+cast
__global__ void transpose_cast_kernel(const float* __restrict__ W, u16* __restrict__ Wt) {
  __shared__ float tile[32][33];
  const int tx = threadIdx.x;          // 0..31
  const int ty = threadIdx.y;          // 0..7
  const int n0 = blockIdx.x * 32;
  const int k0 = blockIdx.y * 32;
#pragma unroll
  for (int i = 0; i < 4; ++i)
    tile[ty + i * 8][tx] = W[(size_t)(k0 + ty + i * 8) * DM + n0 + tx];
  __syncthreads();
#pragma unroll
  for (int i = 0; i < 4; ++i)
    Wt[(size_t)(n0 + ty + i * 8) * DM + k0 + tx] = f2bf(tile[tx][ty + i * 8]);
}

// ---------------------------------------------------------------- valid_len from key padding mask
__global__ void vlen_kernel(const int* __restrict__ mask, int* __restrict__ vlen) {
  const int b = blockIdx.x;
  const int t = threadIdx.x;
  __shared__ int cnt[256];
  int c = 0;
  for (int s = t; s < SEQ; s += 256) c += (mask[b * SEQ + s] == 0) ? 1 : 0;
  cnt[t] = c;
  __syncthreads();
  for (int off = 128; off > 0; off >>= 1) {
    if (t < off) cnt[t] += cnt[t + off];
    __syncthreads();
  }
  if (t == 0) vlen[b] = cnt[0];
}

// ---------------------------------------------------------------- 128x128 MFMA GEMM
template <bool A_FP32>
__global__ __launch_bounds__(256) void gemm_kernel(const void* __restrict__ Av,
                                                   const u16* __restrict__ Bt,
                                                   const float* __restrict__ bias,
                                                   void* __restrict__ outv,
                                                   int out_mode) {
  __shared__ __align__(16) u16 lds_a[128 * LSTR];
  __shared__ __align__(16) u16 lds_b[128 * LSTR];
  const int tid  = threadIdx.x;
  const int lane = tid & 63;
  const int w    = tid >> 6;
  const int wm   = (w >> 1) * 64;
  const int wn   = (w & 1) * 64;
  const int lrow = lane & 15;
  const int lk   = (lane >> 4) * 8;
  const int n0   = blockIdx.x * 128;
  const int m0   = blockIdx.y * 128;

  f32x4 acc[4][4] = {};

  for (int kt = 0; kt < GK; kt += BK) {
    __syncthreads();
    if (A_FP32) {
      const float* A = (const float*)Av;
#pragma unroll
      for (int i = 0; i < 8; ++i) {
        int idx = tid + i * 256;
        int row = idx >> 4, q = idx & 15;
        float4 v = *(const float4*)(A + (size_t)(m0 + row) * GK + kt + q * 4);
        u16x4v hv = {f2bf(v.x), f2bf(v.y), f2bf(v.z), f2bf(v.w)};
        *(u16x4v*)(&lds_a[row * LSTR + q * 4]) = hv;
      }
    } else {
      const u16* A = (const u16*)Av;
#pragma unroll
      for (int i = 0; i < 4; ++i) {
        int idx = tid + i * 256;
        int row = idx >> 3, q = idx & 7;
        *(u16x8*)(&lds_a[row * LSTR + q * 8]) =
            *(const u16x8*)(A + (size_t)(m0 + row) * GK + kt + q * 8);
      }
    }
#pragma unroll
    for (int i = 0; i < 4; ++i) {
      int idx = tid + i * 256;
      int row = idx >> 3, q = idx & 7;
      *(u16x8*)(&lds_b[row * LSTR + q * 8]) =
          *(const u16x8*)(Bt + (size_t)(n0 + row) * GK + kt + q * 8);
    }
    __syncthreads();
#pragma unroll
    for (int kk = 0; kk < BK; kk += 32) {
      u16x8 am[4], bn[4];
#pragma unroll
      for (int m = 0; m < 4; ++m)
        am[m] = *(const u16x8*)(&lds_a[(wm + m * 16 + lrow) * LSTR + kk + lk]);
#pragma unroll
      for (int n = 0; n < 4; ++n)
        bn[n] = *(const u16x8*)(&lds_b[(wn + n * 16 + lrow) * LSTR + kk + lk]);
#pragma unroll
      for (int m = 0; m < 4; ++m)
#pragma unroll
        for (int n = 0; n < 4; ++n)
          acc[m][n] = mfma16(am[m], bn[n], acc[m][n]);
    }
  }

  const int r0 = (lane >> 4) * 4;
#pragma unroll
  for (int m = 0; m < 4; ++m) {
#pragma unroll
    for (int n = 0; n < 4; ++n) {
      const int col = n0 + wn + n * 16 + lrow;
      const float bval = bias[col];
#pragma unroll
      for (int r = 0; r < 4; ++r) {
        const int row = m0 + wm + m * 16 + r0 + r;
        const float v = acc[m][n][r] + bval;
        if (out_mode == 2) {
          ((float*)outv)[(size_t)row * DM + col] = v;
        } else {
          const int bb = row >> 11, s = row & (SEQ - 1);
          const int h = col >> 6, d = col & 63;
          size_t off;
          if (out_mode == 0) off = (((size_t)(bb * NH + h)) * SEQ + s) * 64 + d;
          else               off = (((size_t)(bb * NH + h)) * 64 + d) * SEQ + s;
          ((u16*)outv)[off] = f2bf(v);
        }
      }
    }
  }
}

// ---------------------------------------------------------------- flash attention (swapped-QK 32x32)
// Q,K: bf16 [B,H,S,64]; Vt: bf16 [B,H,64,S]; att out: bf16 [B,S,H*64]
// 4 waves x 32 q-rows = 128 q per block. KVBLK=64.
__global__ __launch_bounds__(256) void attn_kernel(const u16* __restrict__ Qm,
                                                   const u16* __restrict__ Km,
                                                   const u16* __restrict__ Vtm,
                                                   const int* __restrict__ vlen,
                                                   u16* __restrict__ att) {
  __shared__ __align__(16) u16 smem[8192];            // 16 KB
  char* lds_k = (char*)smem;                          // K tile  [64 k][64 dh], swizzled
  char* lds_v = (char*)smem + 8192;                   // Vt tile [64 d][64 k],  swizzled
  const int tid  = threadIdx.x;
  const int lane = tid & 63;
  const int w    = tid >> 6;
  const int ql   = lane & 31;          // q (QK/PV output col), also A-row within tile
  const int hi   = lane >> 5;
  const int hi4  = hi * 4;
  const int qb   = blockIdx.x;
  const int bh   = blockIdx.y;
  const int b    = bh >> 4;
  const int h    = bh & 15;
  const int valid = vlen[b];
  const int q0   = qb * 128;
  const int q0w  = q0 + w * 32;
  const int qg   = q0w + ql;           // this lane's q row
  constexpr float SC = 0.18033688011112042f;  // 0.125 * log2(e)
  const float NEGB = -1e30f;

  // Q fragments (B-operand): col=q=ql, kdim dh = s*16 + hi*8 + j  -> contiguous 16B
  const u16* Qbase = Qm + ((size_t)bh * SEQ + qg) * 64 + hi * 8;
  u16x8 qf[4];
#pragma unroll
  for (int s = 0; s < 4; ++s) qf[s] = *(const u16x8*)(Qbase + s * 16);

  f32x16 acc_o[2] = {};                // O^T: lane holds q=ql, rows d=crow(reg,hi)+32*dc
  float m_run = NEGB, l_run = 0.f;

  const int kb_max = min((q0 + 127) >> 6, (valid - 1) >> 6);
  const int rel_base = min(qg, valid - 1);

  const u16* Kg = Km + (size_t)bh * SEQ * 64;
  const u16* Vg = Vtm + (size_t)bh * 64 * SEQ;

  for (int kb = 0; kb <= kb_max; ++kb) {
    __syncthreads();
    // stage K and V^T tiles (swizzled: byte ^= (row&7)<<4)
#pragma unroll
    for (int i = 0; i < 2; ++i) {
      const int seg = tid + i * 256;   // 512 segs of 16B per tile
      const int row = seg >> 3, c = seg & 7;
      const int dst = (row * 128 + c * 16) ^ ((row & 7) << 4);
      *(u16x8*)(lds_k + dst) = *(const u16x8*)(Kg + ((size_t)(kb * 64 + row)) * 64 + c * 8);
      *(u16x8*)(lds_v + dst) = *(const u16x8*)(Vg + (size_t)row * SEQ + kb * 64 + c * 8);
    }
    __syncthreads();

    if (kb * 64 > q0w + 31) continue;  // tile fully masked for this wave (wave-uniform)

    // ---- QK^T: S^T[k][q], chunk ch covers k = kb*64 + ch*32 + crow(reg,hi)
    f32x16 s_acc[2] = {};
    __builtin_amdgcn_s_setprio(1);
#pragma unroll
    for (int ch = 0; ch < 2; ++ch) {
#pragma unroll
      for (int s = 0; s < 4; ++s) {
        const int krow = ch * 32 + ql;
        const int off = (krow * 128 + s * 32 + hi * 16) ^ ((krow & 7) << 4);
        u16x8 kf = *(const u16x8*)(lds_k + off);
        s_acc[ch] = mfma32(kf, qf[s], s_acc[ch]);
      }
    }
    __builtin_amdgcn_s_setprio(0);

    // ---- mask + online softmax (log2 domain, lane-local per q)
    const int rel = rel_base - kb * 64;
    float mrow = NEGB;
#pragma unroll
    for (int ch = 0; ch < 2; ++ch)
#pragma unroll
      for (int r = 0; r < 16; ++r) {
        const int koff = ch * 32 + (r & 3) + 8 * (r >> 2) + hi4;
        float tv = s_acc[ch][r] * SC;
        tv = (koff > rel) ? NEGB : tv;
        s_acc[ch][r] = tv;
        mrow = fmaxf(mrow, tv);
      }
    mrow = fmaxf(mrow, __shfl_xor(mrow, 32));
    const float mnew = fmaxf(m_run, mrow);
    const float sc_o = fast_exp2(m_run - mnew);
    m_run = mnew;
    float rs = 0.f;
#pragma unroll
    for (int ch = 0; ch < 2; ++ch)
#pragma unroll
      for (int r = 0; r < 16; ++r) {
        const float p = fast_exp2(s_acc[ch][r] - mnew);
        s_acc[ch][r] = p;
        rs += p;
      }
    rs += __shfl_xor(rs, 32);
    l_run = l_run * sc_o + rs;
#pragma unroll
    for (int dc = 0; dc < 2; ++dc)
#pragma unroll
      for (int r = 0; r < 16; ++r) acc_o[dc][r] *= sc_o;

    // ---- P^T -> B-operand frags via cvt_pk + permlane32_swap
    u16x8 pa[4];
#pragma unroll
    for (int ch = 0; ch < 2; ++ch) {
#pragma unroll
      for (int half = 0; half < 2; ++half) {
        const int pb = half * 8;
        u32 x0 = cvt_pk_bf16(s_acc[ch][pb + 0], s_acc[ch][pb + 1]);
        u32 x1 = cvt_pk_bf16(s_acc[ch][pb + 2], s_acc[ch][pb + 3]);
        u32 y0 = cvt_pk_bf16(s_acc[ch][pb + 4], s_acc[ch][pb + 5]);
        u32 y1 = cvt_pk_bf16(s_acc[ch][pb + 6], s_acc[ch][pb + 7]);
        u32x2 r0 = __builtin_amdgcn_permlane32_swap(x0, y0, false, false);
        u32x2 r1 = __builtin_amdgcn_permlane32_swap(x1, y1, false, false);
        u32x4 wds = {r0[0], r1[0], r0[1], r1[1]};
        pa[ch * 2 + half] = __builtin_bit_cast(u16x8, wds);
      }
    }

    // ---- PV: O^T[d][q] += V^T[d][k] * P^T[k][q]
    __builtin_amdgcn_s_setprio(1);
#pragma unroll
    for (int dc = 0; dc < 2; ++dc) {
#pragma unroll
      for (int ks = 0; ks < 4; ++ks) {
        const int drow = dc * 32 + ql;
        const int off = (drow * 128 + ks * 32 + hi * 16) ^ ((drow & 7) << 4);
        u16x8 vf = *(const u16x8*)(lds_v + off);
        acc_o[dc] = mfma32(vf, pa[ks], acc_o[dc]);
      }
    }
    __builtin_amdgcn_s_setprio(0);
  }

  // ---- epilogue: normalize, transpose via LDS, coalesced store
  __syncthreads();
  const float inv_l = 1.f / l_run;
  char* wbase = (char*)smem + w * 4096;   // per-wave 32q x 64d bf16 region
#pragma unroll
  for (int dc = 0; dc < 2; ++dc)
#pragma unroll
    for (int rg = 0; rg < 4; ++rg) {
      u32 lo  = cvt_pk_bf16(acc_o[dc][rg * 4 + 0] * inv_l, acc_o[dc][rg * 4 + 1] * inv_l);
      u32 hiw = cvt_pk_bf16(acc_o[dc][rg * 4 + 2] * inv_l, acc_o[dc][rg * 4 + 3] * inv_l);
      const int dbase = dc * 32 + rg * 8 + hi4;
      const int off = (ql * 128 + dbase * 2) ^ ((ql & 7) << 4);
      u32x2 pr = {lo, hiw};
      *(u32x2*)(wbase + off) = pr;
    }
  __syncthreads();
  u16* attb = att + ((size_t)b * SEQ + q0) * DM + h * 64;
#pragma unroll
  for (int i = 0; i < 4; ++i) {
    const int seg = tid + i * 256;       // 1024 segs of 16B
    const int qr = seg >> 3, c = seg & 7;
    const int off = ((qr & 31) * 128 + c * 16) ^ ((qr & 7) << 4);
    u16x8 vvv = *(const u16x8*)((char*)smem + (qr >> 5) * 4096 + off);
    *(u16x8*)(attb + (size_t)qr * DM + c * 8) = vvv;
  }
}

// ---------------------------------------------------------------- launch
extern "C" void kernel_launch(void* const* d_in, const int* in_sizes, int n_in,
                              void* d_out, int out_size, void* d_ws, size_t ws_size,
                              hipStream_t stream) {
  const float* q_in = (const float*)d_in[0];
  const float* k_in = (const float*)d_in[1];
  const float* v_in = (const float*)d_in[2];
  const int*   kpm  = (const int*)d_in[3];
  const float* Wq   = (const float*)d_in[4];
  const float* bq   = (const float*)d_in[5];
  const float* Wk   = (const float*)d_in[6];
  const float* bk   = (const float*)d_in[7];
  const float* Wv   = (const float*)d_in[8];
  const float* bv   = (const float*)d_in[9];
  const float* Wo   = (const float*)d_in[10];
  const float* bo   = (const float*)d_in[11];

  char* ws = (char*)d_ws;
  const size_t WSZ = (size_t)1 << 21;   // 2 MB per transposed weight
  const size_t TSZ = (size_t)1 << 24;   // 16 MB per bf16 [8192,1024] tensor
  u16* wq_t = (u16*)(ws);
  u16* wk_t = (u16*)(ws + WSZ);
  u16* wv_t = (u16*)(ws + 2 * WSZ);
  u16* wo_t = (u16*)(ws + 3 * WSZ);
  u16* Qm   = (u16*)(ws + 4 * WSZ);
  u16* Km   = (u16*)(ws + 4 * WSZ + TSZ);
  u16* Vtm  = (u16*)(ws + 4 * WSZ + 2 * TSZ);
  u16* attb = (u16*)(ws + 4 * WSZ + 3 * TSZ);
  int* vlen = (int*)(ws + 4 * WSZ + 4 * TSZ);

  dim3 tb(32, 8), tg(32, 32);
  transpose_cast_kernel<<<tg, tb, 0, stream>>>(Wq, wq_t);
  transpose_cast_kernel<<<tg, tb, 0, stream>>>(Wk, wk_t);
  transpose_cast_kernel<<<tg, tb, 0, stream>>>(Wv, wv_t);
  transpose_cast_kernel<<<tg, tb, 0, stream>>>(Wo, wo_t);
  vlen_kernel<<<NB, 256, 0, stream>>>(kpm, vlen);

  dim3 gg(8, 64);
  gemm_kernel<true><<<gg, 256, 0, stream>>>(q_in, wq_t, bq, Qm, 0);
  gemm_kernel<true><<<gg, 256, 0, stream>>>(k_in, wk_t, bk, Km, 0);
  gemm_kernel<true><<<gg, 256, 0, stream>>>(v_in, wv_t, bv, Vtm, 1);

  attn_kernel<<<dim3(16, 64), 256, 0, stream>>>(Qm, Km, Vtm, vlen, attb);

  gemm_kernel<false><<<gg, 256, 0, stream>>>(attb, wo_t, bo, d_out, 2);
}